// Round 7
// baseline (244.145 us; speedup 1.0000x reference)
//
#include <hip/hip_runtime.h>

typedef __bf16 bf16x8 __attribute__((ext_vector_type(8)));
typedef float f32x4 __attribute__((ext_vector_type(4)));
typedef float f32x16 __attribute__((ext_vector_type(16)));

#define BATCH 4
#define SEQ   2048
#define DIM   1024
#define NH    16
#define HD    64
#define ECF   0.18033688f   // log2(e)/8 : folds 1/sqrt(64) into exp2

__device__ __forceinline__ unsigned short f2bf(float f) {
  union { float f; unsigned u; } v; v.f = f;
  unsigned u = v.u;
  u += 0x7FFF + ((u >> 16) & 1);   // round-to-nearest-even
  return (unsigned short)(u >> 16);
}

__device__ __forceinline__ void g2lds16(const unsigned short* g, unsigned short* l) {
  __builtin_amdgcn_global_load_lds(
      (const __attribute__((address_space(1))) unsigned int*)g,
      (__attribute__((address_space(3))) unsigned int*)l, 16, 0, 0);
}

// scalar-cast pack (compiler emits v_cvt_pk_bf16_f32)
__device__ __forceinline__ unsigned packbf(float a, float b) {
  __bf16 lo = (__bf16)a, hi = (__bf16)b;
  unsigned short ul = __builtin_bit_cast(unsigned short, lo);
  unsigned short uh = __builtin_bit_cast(unsigned short, hi);
  return (unsigned)ul | ((unsigned)uh << 16);
}

// ------------- fused cast fp32 -> bf16 (x, Wq*EC, Wk, Wv) -------------
__global__ __launch_bounds__(256) void cast_all_kernel(
    const float* __restrict__ x,  const float* __restrict__ Wq,
    const float* __restrict__ Wk, const float* __restrict__ Wv,
    unsigned short* __restrict__ xb,  unsigned short* __restrict__ wqb,
    unsigned short* __restrict__ wkb, unsigned short* __restrict__ wvb) {
  const int XG = (BATCH * SEQ * DIM) / 8;   // 1048576
  const int WG = (DIM * DIM) / 8;           // 131072
  int i = blockIdx.x * 256 + threadIdx.x;
  const float* in; unsigned short* out; float sc = 1.0f; int off;
  if (i < XG)               { in = x;  out = xb;  off = i; }
  else if (i < XG + WG)     { in = Wq; out = wqb; off = i - XG; sc = ECF; }
  else if (i < XG + 2 * WG) { in = Wk; out = wkb; off = i - XG - WG; }
  else                      { in = Wv; out = wvb; off = i - XG - 2 * WG; }
  const float4* p = (const float4*)in + (size_t)off * 2;
  float4 a = p[0], b = p[1];
  unsigned short r[8];
  r[0] = f2bf(a.x * sc); r[1] = f2bf(a.y * sc); r[2] = f2bf(a.z * sc); r[3] = f2bf(a.w * sc);
  r[4] = f2bf(b.x * sc); r[5] = f2bf(b.y * sc); r[6] = f2bf(b.z * sc); r[7] = f2bf(b.w * sc);
  *(uint4*)&out[(size_t)off * 8] = *(uint4*)r;
}

// -------- fused QKV projection GEMM: 256x128 tile, BK=64, 2-phase -----
// (R11 structure, kept: counted-vmcnt triple-buffer, setprio MFMA clusters)
__global__ __launch_bounds__(512, 1) void gemm_qkv(
    const unsigned short* __restrict__ A,
    const unsigned short* __restrict__ Wqp, const unsigned short* __restrict__ Wkp,
    const unsigned short* __restrict__ Wvp,
    const float* __restrict__ bqp, const float* __restrict__ bkp,
    const float* __restrict__ bvp,
    unsigned short* __restrict__ oq, unsigned short* __restrict__ ok,
    unsigned short* __restrict__ ov) {
  __shared__ __align__(16) unsigned short sm[3 * 24576];   // 144KB

  const int z = blockIdx.z;
  const unsigned short* W = (z == 0) ? Wqp : (z == 1) ? Wkp : Wvp;
  const float* bias        = (z == 0) ? bqp : (z == 1) ? bkp : bvp;
  unsigned short* outp     = (z == 0) ? oq  : (z == 1) ? ok  : ov;
  const float bsc          = (z == 0) ? ECF : 1.0f;
  const int mode = (z == 2) ? 1 : 0;

  const int tid  = threadIdx.x;
  const int w    = tid >> 6;
  const int lane = tid & 63;
  const int lm   = lane & 15;
  const int qd   = lane >> 4;
  const int m0 = blockIdx.x * 256;
  const int n0 = blockIdx.y * 128;
  const int wm = (w & 3) * 64;
  const int wn = (w >> 2) * 64;

  f32x4 acc[4][4];
#pragma unroll
  for (int i = 0; i < 4; ++i)
#pragma unroll
    for (int j = 0; j < 4; ++j) acc[i][j] = {0.f, 0.f, 0.f, 0.f};

  const int r0 = tid >> 3;
  const int sp = ((tid & 7) ^ (r0 & 7)) * 8;

#define SA(buf, t4, i) g2lds16(&A[(size_t)(m0 + r0 + 64*(i)) * DIM + (t4)*64 + sp], \
                               &sm[(buf)*24576 + (r0 + 64*(i))*64 + (tid & 7)*8])
#define SB(buf, t4, i) g2lds16(&W[(size_t)(n0 + r0 + 64*(i)) * DIM + (t4)*64 + sp], \
                               &sm[(buf)*24576 + 16384 + (r0 + 64*(i))*64 + (tid & 7)*8])
#define BARR() asm volatile("s_barrier" ::: "memory")

  const int rk = lm & 7;

  SA(0, 0, 0); SA(0, 0, 1); SA(0, 0, 2); SA(0, 0, 3); SB(0, 0, 0); SB(0, 0, 1);
  SA(1, 1, 0); SA(1, 1, 1); SA(1, 1, 2); SA(1, 1, 3); SB(1, 1, 0); SB(1, 1, 1);
  asm volatile("s_waitcnt vmcnt(6)" ::: "memory");
  BARR();

  for (int t = 0; t < DIM / 64; ++t) {
    const int cur = t % 3;
    const int nb  = (t + 2) % 3;
    const bool st = (t + 2) < DIM / 64;
    const unsigned short* Ab = &sm[cur * 24576];
    const unsigned short* Bb = &sm[cur * 24576 + 16384];

    {
      bf16x8 af[4], bfr[4];
#pragma unroll
      for (int i = 0; i < 4; ++i)
        af[i]  = *(const bf16x8*)&Ab[(wm + i * 16 + lm) * 64 + ((qd ^ rk) * 8)];
#pragma unroll
      for (int j = 0; j < 4; ++j)
        bfr[j] = *(const bf16x8*)&Bb[(wn + j * 16 + lm) * 64 + ((qd ^ rk) * 8)];
      if (st) { SA(nb, t + 2, 0); SA(nb, t + 2, 1); SA(nb, t + 2, 2); }
      BARR();
      __builtin_amdgcn_s_setprio(1);
#pragma unroll
      for (int i = 0; i < 4; ++i)
#pragma unroll
        for (int j = 0; j < 4; ++j)
          acc[i][j] = __builtin_amdgcn_mfma_f32_16x16x32_bf16(af[i], bfr[j], acc[i][j], 0, 0, 0);
      __builtin_amdgcn_s_setprio(0);
      BARR();
    }
    {
      bf16x8 af[4], bfr[4];
#pragma unroll
      for (int i = 0; i < 4; ++i)
        af[i]  = *(const bf16x8*)&Ab[(wm + i * 16 + lm) * 64 + (((4 + qd) ^ rk) * 8)];
#pragma unroll
      for (int j = 0; j < 4; ++j)
        bfr[j] = *(const bf16x8*)&Bb[(wn + j * 16 + lm) * 64 + (((4 + qd) ^ rk) * 8)];
      if (st) { SA(nb, t + 2, 3); SB(nb, t + 2, 0); SB(nb, t + 2, 1); }
      BARR();
      __builtin_amdgcn_s_setprio(1);
#pragma unroll
      for (int i = 0; i < 4; ++i)
#pragma unroll
        for (int j = 0; j < 4; ++j)
          acc[i][j] = __builtin_amdgcn_mfma_f32_16x16x32_bf16(af[i], bfr[j], acc[i][j], 0, 0, 0);
      __builtin_amdgcn_s_setprio(0);
      if (st) asm volatile("s_waitcnt vmcnt(6)" ::: "memory");
      else    asm volatile("s_waitcnt vmcnt(0)" ::: "memory");
      BARR();
    }
  }
#undef SA
#undef SB
#undef BARR

#pragma unroll
  for (int j = 0; j < 4; ++j) {
    int col = n0 + wn + j * 16 + lm;
    float bb = bias[col] * bsc;
    int h = col >> 6, hd = col & 63;
#pragma unroll
    for (int i = 0; i < 4; ++i) {
      int rowb = m0 + wm + i * 16 + qd * 4;
      int b = rowb >> 11, s = rowb & 2047;
      if (mode == 0) {
#pragma unroll
        for (int r = 0; r < 4; ++r) {
          float v = acc[i][j][r] + bb;
          outp[((size_t)(b * NH + h) * SEQ + (s + r)) * HD + hd] = f2bf(v);
        }
      } else {
        unsigned short pk[4];
#pragma unroll
        for (int r = 0; r < 4; ++r) pk[r] = f2bf(acc[i][j][r] + bb);
        size_t idx = ((size_t)(b * NH + h) * HD + hd) * SEQ + s;
        *(uint2*)&outp[idx] = *(uint2*)pk;
      }
    }
  }
}

// ------ flash attention R12: FREE-RUNNING WAVES, zero barriers --------
// R6-R10 post-mortem: every variant with block-wide staging barriers lands
// at 96-99us -- the collective vmcnt(0)+s_barrier drain phase-locks all
// waves to the slowest's serial chain. Here each wave is fully independent:
//  * per-wave PRIVATE LDS (K 8KB + V 8KB, single-buffered); g2lds
//    completion tracked by the wave's own vmcnt -- NO s_barrier anywhere.
//  * buffer reuse ordered by same-wave lgkmcnt(0)+sched_barrier(0) after
//    frag reads (rule 18), then stage(t+1) issues; remaining ~900cyc of
//    tile-t compute covers the load latency (prefetch without dbuf).
//  * softmax = R6's proven in-register path (32x32 MFMA, swapped QK^T,
//    cvt_pk+permlane32_swap, no Ps round-trip).
//  * block = 2 independent waves, 33KB LDS -> 4 blocks/CU = 8 waves/CU;
//    ALL 2048 waves resident simultaneously, drift freely across phases.
__global__ __launch_bounds__(128, 2) void flash_kernel(
    const unsigned short* __restrict__ Qp, const unsigned short* __restrict__ Kp,
    const unsigned short* __restrict__ Vp, float* __restrict__ out) {
  __shared__ __align__(16) unsigned short Ksm[2][64 * 64];  // per-wave K tile
  __shared__ __align__(16) unsigned short Vsm[2][64 * 64];  // per-wave V tile
  __shared__ float Ls[2][2][32];

  const int tid  = threadIdx.x;   // 0..127
  const int w    = tid >> 6;      // wave 0..1 (independent)
  const int lane = tid & 63;
  const int l31  = lane & 31;
  const int hi   = lane >> 5;
  const int bh   = blockIdx.y;
  const int wq0  = blockIdx.x * 128 + w * 64;

  const unsigned short* Qb = Qp + (size_t)bh * (SEQ * HD);
  const unsigned short* Kb = Kp + (size_t)bh * (SEQ * HD);
  const unsigned short* Vb = Vp + (size_t)bh * (HD * SEQ);
  unsigned short* Kw = &Ksm[w][0];
  unsigned short* Vw = &Vsm[w][0];

  // Q in registers: 64 rows/wave = 2 row-blocks x 4 d-blocks
  bf16x8 qf[2][4];
#pragma unroll
  for (int qb = 0; qb < 2; ++qb)
#pragma unroll
    for (int db = 0; db < 4; ++db)
      qf[qb][db] = *(const bf16x8*)&Qb[(size_t)(wq0 + qb * 32 + l31) * HD + db * 16 + hi * 8];

  f32x16 o[2][2];
#pragma unroll
  for (int qb = 0; qb < 2; ++qb)
#pragma unroll
    for (int jn = 0; jn < 2; ++jn)
#pragma unroll
      for (int r = 0; r < 16; ++r) o[qb][jn][r] = 0.f;
  float psum[2] = {0.f, 0.f};

  // per-wave staging: inst i covers rows i*8..i*8+7, lane -> row i*8+(lane>>3),
  // chunk pos lane&7; source col pre-swizzled ^(row&7) = ^(lane>>3) (rule 21)
  const int srow = lane >> 3;                       // 0..7
  const int sco  = ((lane & 7) ^ srow) * 8;         // swizzled source col (elems)
  const int r7   = l31 & 7;                         // read-side swizzle key

#define STAGE_K(k0) do {                                                      \
    _Pragma("unroll")                                                         \
    for (int i_ = 0; i_ < 8; ++i_)                                            \
      g2lds16(&Kb[(size_t)((k0) + i_ * 8 + srow) * HD + sco],                 \
              &Kw[i_ * 512 + lane * 8]);                                      \
  } while (0)
#define STAGE_V(k0) do {                                                      \
    _Pragma("unroll")                                                         \
    for (int i_ = 0; i_ < 8; ++i_)                                            \
      g2lds16(&Vb[(size_t)(i_ * 8 + srow) * SEQ + (k0) + sco],                \
              &Vw[i_ * 512 + lane * 8]);                                      \
  } while (0)
#define FENCE_LGKM() do {                                                     \
    asm volatile("s_waitcnt lgkmcnt(0)" ::: "memory");                        \
    __builtin_amdgcn_sched_barrier(0);                                        \
  } while (0)

  STAGE_K(0);
  STAGE_V(0);

  for (int kt = 0; kt < SEQ / 64; ++kt) {
    const int k0n = (kt + 1) * 64;
    const bool st = (kt + 1) < SEQ / 64;

    // wait this wave's own K+V staged (issued a full tile ago -> covered)
    asm volatile("s_waitcnt vmcnt(0)" ::: "memory");
    __builtin_amdgcn_sched_barrier(0);

    // ---- latch K frags, then overwrite-stage K(t+1) ----
    bf16x8 kf[2][4];
#pragma unroll
    for (int kb = 0; kb < 2; ++kb)
#pragma unroll
      for (int db = 0; db < 4; ++db)
        kf[kb][db] = *(const bf16x8*)&Kw[((kb * 32 + l31) * 8 + ((db * 2 + hi) ^ r7)) * 8];
    FENCE_LGKM();
    if (st) STAGE_K(k0n);

    // ---- QK^T + in-register softmax-numerator (R6 math) ----
    bf16x8 pa[2][4];
#pragma unroll
    for (int kb = 0; kb < 2; ++kb) {
      f32x16 s0 = {0,0,0,0,0,0,0,0,0,0,0,0,0,0,0,0};
      f32x16 s1 = {0,0,0,0,0,0,0,0,0,0,0,0,0,0,0,0};
      __builtin_amdgcn_s_setprio(1);
#pragma unroll
      for (int db = 0; db < 4; ++db) {
        s0 = __builtin_amdgcn_mfma_f32_32x32x16_bf16(kf[kb][db], qf[0][db], s0, 0, 0, 0);
        s1 = __builtin_amdgcn_mfma_f32_32x32x16_bf16(kf[kb][db], qf[1][db], s1, 0, 0, 0);
      }
      __builtin_amdgcn_s_setprio(0);
#pragma unroll
      for (int qb = 0; qb < 2; ++qb) {
        const f32x16 s = qb ? s1 : s0;
        float p[16];
#pragma unroll
        for (int r = 0; r < 16; ++r) p[r] = __builtin_amdgcn_exp2f(s[r]);
        psum[qb] += ((p[0] + p[1]) + (p[2] + p[3])) + ((p[4] + p[5]) + (p[6] + p[7]))
                  + ((p[8] + p[9]) + (p[10] + p[11])) + ((p[12] + p[13]) + (p[14] + p[15]));
        unsigned w01 = packbf(p[0],  p[1]),  w23 = packbf(p[2],  p[3]);
        unsigned w45 = packbf(p[4],  p[5]),  w67 = packbf(p[6],  p[7]);
        unsigned w89 = packbf(p[8],  p[9]),  wab = packbf(p[10], p[11]);
        unsigned wcd = packbf(p[12], p[13]), wef = packbf(p[14], p[15]);
        asm volatile("v_permlane32_swap_b32 %0, %1" : "+v"(w01), "+v"(w45));
        asm volatile("v_permlane32_swap_b32 %0, %1" : "+v"(w23), "+v"(w67));
        asm volatile("v_permlane32_swap_b32 %0, %1" : "+v"(w89), "+v"(wcd));
        asm volatile("v_permlane32_swap_b32 %0, %1" : "+v"(wab), "+v"(wef));
        union { unsigned u[4]; bf16x8 v; } flo, fhi;
        flo.u[0] = w01; flo.u[1] = w23; flo.u[2] = w45; flo.u[3] = w67;
        fhi.u[0] = w89; fhi.u[1] = wab; fhi.u[2] = wcd; fhi.u[3] = wef;
        pa[qb][kb * 2]     = flo.v;
        pa[qb][kb * 2 + 1] = fhi.v;
      }
    }

    // ---- latch V frags, then overwrite-stage V(t+1) ----
    bf16x8 vf[4][2];
#pragma unroll
    for (int ks = 0; ks < 4; ++ks)
#pragma unroll
      for (int jn = 0; jn < 2; ++jn)
        vf[ks][jn] = *(const bf16x8*)&Vw[((jn * 32 + l31) * 8 + ((ks * 2 + hi) ^ r7)) * 8];
    FENCE_LGKM();
    if (st) STAGE_V(k0n);

    // ---- O += P V ----
    __builtin_amdgcn_s_setprio(1);
#pragma unroll
    for (int ks = 0; ks < 4; ++ks)
#pragma unroll
      for (int jn = 0; jn < 2; ++jn) {
        o[0][jn] = __builtin_amdgcn_mfma_f32_32x32x16_bf16(pa[0][ks], vf[ks][jn], o[0][jn], 0, 0, 0);
        o[1][jn] = __builtin_amdgcn_mfma_f32_32x32x16_bf16(pa[1][ks], vf[ks][jn], o[1][jn], 0, 0, 0);
      }
    __builtin_amdgcn_s_setprio(0);
  }

  // row-sum across the two key-halves (lane l and l^32 share qrow=l31)
#pragma unroll
  for (int qb = 0; qb < 2; ++qb) {
    float l = psum[qb] + __shfl_xor(psum[qb], 32);
    if (hi == 0) Ls[w][qb][l31] = 1.0f / l;
  }
  asm volatile("s_waitcnt lgkmcnt(0)" ::: "memory");   // same-wave LDS RAW

  const int b = bh >> 4, hh = bh & 15;
#pragma unroll
  for (int qb = 0; qb < 2; ++qb)
#pragma unroll
    for (int r = 0; r < 16; ++r) {
      int crow = (r & 3) + 8 * (r >> 2) + 4 * hi;
      float inv = Ls[w][qb][crow];
      int qrow = wq0 + qb * 32 + crow;
      float* po = &out[(size_t)(b * SEQ + qrow) * DIM + hh * HD + l31];
      po[0]  = o[qb][0][r] * inv;
      po[32] = o[qb][1][r] * inv;
    }
#undef STAGE_K
#undef STAGE_V
#undef FENCE_LGKM
}

extern "C" void kernel_launch(void* const* d_in, const int* in_sizes, int n_in,
                              void* d_out, int out_size, void* d_ws, size_t ws_size,
                              hipStream_t stream) {
  const float* x  = (const float*)d_in[0];
  const float* Wq = (const float*)d_in[1];
  const float* bq = (const float*)d_in[2];
  const float* Wk = (const float*)d_in[3];
  const float* bk = (const float*)d_in[4];
  const float* Wv = (const float*)d_in[5];
  const float* bv = (const float*)d_in[6];
  float* out = (float*)d_out;

  unsigned short* ws = (unsigned short*)d_ws;
  const size_t XE = (size_t)BATCH * SEQ * DIM;   // 8388608
  const size_t WE = (size_t)DIM * DIM;           // 1048576
  unsigned short* xb  = ws;
  unsigned short* wqb = xb + XE;
  unsigned short* wkb = wqb + WE;
  unsigned short* wvb = wkb + WE;
  unsigned short* qb  = wvb + WE;
  unsigned short* kb  = qb + XE;
  unsigned short* vb  = kb + XE;

  const int total_groups = (int)(XE / 8 + 3 * (WE / 8));   // 1441792
  cast_all_kernel<<<total_groups / 256, 256, 0, stream>>>(
      x, Wq, Wk, Wv, xb, wqb, wkb, wvb);

  dim3 gg(32, 8, 3);
  gemm_qkv<<<gg, 512, 0, stream>>>(xb, wqb, wkb, wvb, bq, bk, bv, qb, kb, vb);

  dim3 fg(SEQ / 128, BATCH * NH);
  flash_kernel<<<fg, 128, 0, stream>>>(qb, kb, vb, out);
}